// Round 3
// baseline (207.841 us; speedup 1.0000x reference)
//
#include <hip/hip_runtime.h>

#define BLOCK   256
#define B_ROWS  131072
#define C_COLS  128
#define K_SEL   64
#define TOTAL_VEC (B_ROWS * C_COLS / 4)          // 4,194,304 float4
#define NTHREADS  (TOTAL_VEC / 2)                // 2 float4 per thread
#define GRID      (NTHREADS / BLOCK)             // 8192 blocks

// d_ws layout:
//   [0    .. 512)   : float w[128]      (column weight table)
//   [1024 .. 1024+GRID*8) : float2 partials[GRID]
#define WS_PARTIALS_OFF 1024

__global__ void build_w(const int* __restrict__ class_idx,
                        float* __restrict__ w)
{
    int c = threadIdx.x;                 // 128 threads
    int cnt = 0;
    #pragma unroll
    for (int k = 0; k < K_SEL; ++k)
        cnt += (class_idx[k] == c) ? 1 : 0;
    w[c] = (float)cnt;
}

__device__ __forceinline__ float fast_log(float x) {
    return __log2f(x) * 0.6931471805599453f;     // v_log_f32 + mul
}

__device__ __forceinline__ float per_elem_loss(float o, float oc, float y,
                                               float wc) {
    float sharp = (o > 0.5f) ? (o + (1.0f - o) * 0.25f)
                             : (o - o * 0.25f);
    float lo  = fmaxf(fast_log(o),        -100.0f);
    float l1o = fmaxf(fast_log(1.0f - o), -100.0f);
    float bce = -(y * lo + (1.0f - y) * l1o);
    float dp = o  - sharp;
    float dc = oc - sharp;
    return wc * (bce + dp * dp + dc * dc);
}

__global__ __launch_bounds__(BLOCK) void semi_loss_main(
    const float* __restrict__ out,
    const float* __restrict__ outc,
    const float* __restrict__ lab,
    const int*  __restrict__ batch_mask,
    const float* __restrict__ wtab,
    float2* __restrict__ partials)
{
    const int tid = blockIdx.x * BLOCK + threadIdx.x;
    const int v0  = tid;
    const int v1  = tid + NTHREADS;      // NTHREADS % 32 == 0 -> same c4
    const int c4  = v0 & 31;             // float4 index within row

    // Issue ALL loads up front, no dependent branching.
    const int m0 = batch_mask[v0 >> 5];
    const int m1 = batch_mask[v1 >> 5];
    const float4 w4  = ((const float4*)wtab)[c4];

    const float4 o0  = ((const float4*)out )[v0];
    const float4 oc0 = ((const float4*)outc)[v0];
    const float4 y0  = ((const float4*)lab )[v0];
    const float4 o1  = ((const float4*)out )[v1];
    const float4 oc1 = ((const float4*)outc)[v1];
    const float4 y1  = ((const float4*)lab )[v1];

    const float mf0 = m0 ? 1.0f : 0.0f;
    const float mf1 = m1 ? 1.0f : 0.0f;

    float s0 = per_elem_loss(o0.x, oc0.x, y0.x, w4.x)
             + per_elem_loss(o0.y, oc0.y, y0.y, w4.y)
             + per_elem_loss(o0.z, oc0.z, y0.z, w4.z)
             + per_elem_loss(o0.w, oc0.w, y0.w, w4.w);
    float s1 = per_elem_loss(o1.x, oc1.x, y1.x, w4.x)
             + per_elem_loss(o1.y, oc1.y, y1.y, w4.y)
             + per_elem_loss(o1.z, oc1.z, y1.z, w4.z)
             + per_elem_loss(o1.w, oc1.w, y1.w, w4.w);

    float sum  = mf0 * s0 + mf1 * s1;
    float cntf = (c4 == 0) ? (mf0 + mf1) : 0.0f;   // each row counted once

    // wave (64) shuffle reduction, then LDS across the block's 4 waves
    #pragma unroll
    for (int off = 32; off > 0; off >>= 1) {
        sum  += __shfl_down(sum,  off);
        cntf += __shfl_down(cntf, off);
    }
    __shared__ float ssum[BLOCK / 64];
    __shared__ float scnt[BLOCK / 64];
    int wave = threadIdx.x >> 6;
    int lane = threadIdx.x & 63;
    if (lane == 0) { ssum[wave] = sum; scnt[wave] = cntf; }
    __syncthreads();
    if (threadIdx.x == 0) {
        float s = 0.0f, c = 0.0f;
        #pragma unroll
        for (int i = 0; i < BLOCK / 64; ++i) { s += ssum[i]; c += scnt[i]; }
        partials[blockIdx.x] = make_float2(s, c);
    }
}

__global__ __launch_bounds__(BLOCK) void semi_loss_reduce(
    const float2* __restrict__ partials, float* __restrict__ out)
{
    double s = 0.0, c = 0.0;
    for (int i = threadIdx.x; i < GRID; i += BLOCK) {
        float2 p = partials[i];
        s += (double)p.x;
        c += (double)p.y;
    }
    #pragma unroll
    for (int off = 32; off > 0; off >>= 1) {
        s += __shfl_down(s, off);
        c += __shfl_down(c, off);
    }
    __shared__ double dsum[BLOCK / 64];
    __shared__ double dcnt[BLOCK / 64];
    int wave = threadIdx.x >> 6;
    int lane = threadIdx.x & 63;
    if (lane == 0) { dsum[wave] = s; dcnt[wave] = c; }
    __syncthreads();
    if (threadIdx.x == 0) {
        double ts = 0.0, tc = 0.0;
        #pragma unroll
        for (int i = 0; i < BLOCK / 64; ++i) { ts += dsum[i]; tc += dcnt[i]; }
        out[0] = (float)(ts / (tc * (double)K_SEL));
    }
}

extern "C" void kernel_launch(void* const* d_in, const int* in_sizes, int n_in,
                              void* d_out, int out_size, void* d_ws, size_t ws_size,
                              hipStream_t stream) {
    const float* out_p  = (const float*)d_in[0];
    const float* outc_p = (const float*)d_in[1];
    const float* lab_p  = (const float*)d_in[2];
    const int*   cidx_p = (const int*)d_in[3];
    const int*   mask_p = (const int*)d_in[4];

    float*  wtab     = (float*)d_ws;
    float2* partials = (float2*)((char*)d_ws + WS_PARTIALS_OFF);

    build_w<<<1, C_COLS, 0, stream>>>(cidx_p, wtab);
    semi_loss_main<<<GRID, BLOCK, 0, stream>>>(out_p, outc_p, lab_p,
                                               mask_p, wtab, partials);
    semi_loss_reduce<<<1, BLOCK, 0, stream>>>(partials, (float*)d_out);
}

// Round 4
// 186.527 us; speedup vs baseline: 1.1143x; 1.1143x over previous
//
#include <hip/hip_runtime.h>

#define BLOCK   256
#define B_ROWS  131072
#define C_COLS  128
#define K_SEL   64
#define ROWS_PER_BLOCK 64
#define GRID    (B_ROWS / ROWS_PER_BLOCK)                 // 2048 blocks
#define F4_PER_BLOCK (ROWS_PER_BLOCK * C_COLS / 4)        // 2048 float4
#define ITERS   (F4_PER_BLOCK / BLOCK)                    // 8 per thread

// d_ws layout:
//   [0    .. 512)  : float w[128]          (column weight table)
//   [1024 .. 1024+GRID*8) : float2 partials[GRID]
#define WS_PARTIALS_OFF 1024

__global__ void build_w(const int* __restrict__ class_idx,
                        float* __restrict__ w)
{
    int c = threadIdx.x;                 // 128 threads
    int cnt = 0;
    #pragma unroll
    for (int k = 0; k < K_SEL; ++k)
        cnt += (class_idx[k] == c) ? 1 : 0;
    w[c] = (float)cnt;
}

__device__ __forceinline__ float fast_log(float x) {
    return __log2f(x) * 0.6931471805599453f;   // v_log_f32 + mul
}

__device__ __forceinline__ float per_elem_loss(float o, float oc, float y,
                                               float wc) {
    float sharp = (o > 0.5f) ? (o + (1.0f - o) * 0.25f)
                             : (o - o * 0.25f);
    float lo  = fmaxf(fast_log(o),        -100.0f);
    float l1o = fmaxf(fast_log(1.0f - o), -100.0f);
    float bce = -(y * lo + (1.0f - y) * l1o);
    float dp = o  - sharp;
    float dc = oc - sharp;
    return wc * (bce + dp * dp + dc * dc);
}

__global__ __launch_bounds__(BLOCK) void semi_loss_main(
    const float* __restrict__ out,
    const float* __restrict__ outc,
    const float* __restrict__ lab,
    const int*  __restrict__ batch_mask,
    const float* __restrict__ wtab,
    float2* __restrict__ partials)
{
    __shared__ float wm[ROWS_PER_BLOCK];

    const int row0 = blockIdx.x * ROWS_PER_BLOCK;
    float cntf = 0.0f;
    if (threadIdx.x < ROWS_PER_BLOCK) {
        float m = batch_mask[row0 + threadIdx.x] ? 1.0f : 0.0f;
        wm[threadIdx.x] = m;
        cntf = m;                        // each row counted exactly once
    }

    const int   c4 = threadIdx.x & 31;   // constant column slot per thread
    const float4 w4 = ((const float4*)wtab)[c4];

    __syncthreads();

    const int vbase = blockIdx.x * F4_PER_BLOCK + threadIdx.x;
    const int rsub  = threadIdx.x >> 5;  // sub-row within iteration group
    float sum = 0.0f;

    #pragma unroll
    for (int i = 0; i < ITERS; ++i) {
        const float m = wm[i * 8 + rsub];    // LDS broadcast, ~30 cyc
        if (m > 0.0f) {
            const int v = vbase + i * BLOCK;
            float4 o4  = ((const float4*)out )[v];
            float4 oc4 = ((const float4*)outc)[v];
            float4 y4  = ((const float4*)lab )[v];
            sum += per_elem_loss(o4.x, oc4.x, y4.x, w4.x)
                 + per_elem_loss(o4.y, oc4.y, y4.y, w4.y)
                 + per_elem_loss(o4.z, oc4.z, y4.z, w4.z)
                 + per_elem_loss(o4.w, oc4.w, y4.w, w4.w);
        }
    }

    // wave (64) shuffle reduction, then LDS across the block's 4 waves
    #pragma unroll
    for (int off = 32; off > 0; off >>= 1) {
        sum  += __shfl_down(sum,  off);
        cntf += __shfl_down(cntf, off);
    }
    __shared__ float ssum[BLOCK / 64];
    __shared__ float scnt[BLOCK / 64];
    int wave = threadIdx.x >> 6;
    int lane = threadIdx.x & 63;
    if (lane == 0) { ssum[wave] = sum; scnt[wave] = cntf; }
    __syncthreads();
    if (threadIdx.x == 0) {
        float s = 0.0f, c = 0.0f;
        #pragma unroll
        for (int i = 0; i < BLOCK / 64; ++i) { s += ssum[i]; c += scnt[i]; }
        partials[blockIdx.x] = make_float2(s, c);
    }
}

__global__ __launch_bounds__(BLOCK) void semi_loss_reduce(
    const float2* __restrict__ partials, float* __restrict__ out)
{
    double s = 0.0, c = 0.0;
    for (int i = threadIdx.x; i < GRID; i += BLOCK) {
        float2 p = partials[i];
        s += (double)p.x;
        c += (double)p.y;
    }
    #pragma unroll
    for (int off = 32; off > 0; off >>= 1) {
        s += __shfl_down(s, off);
        c += __shfl_down(c, off);
    }
    __shared__ double dsum[BLOCK / 64];
    __shared__ double dcnt[BLOCK / 64];
    int wave = threadIdx.x >> 6;
    int lane = threadIdx.x & 63;
    if (lane == 0) { dsum[wave] = s; dcnt[wave] = c; }
    __syncthreads();
    if (threadIdx.x == 0) {
        double ts = 0.0, tc = 0.0;
        #pragma unroll
        for (int i = 0; i < BLOCK / 64; ++i) { ts += dsum[i]; tc += dcnt[i]; }
        out[0] = (float)(ts / (tc * (double)K_SEL));
    }
}

extern "C" void kernel_launch(void* const* d_in, const int* in_sizes, int n_in,
                              void* d_out, int out_size, void* d_ws, size_t ws_size,
                              hipStream_t stream) {
    const float* out_p  = (const float*)d_in[0];
    const float* outc_p = (const float*)d_in[1];
    const float* lab_p  = (const float*)d_in[2];
    const int*   cidx_p = (const int*)d_in[3];
    const int*   mask_p = (const int*)d_in[4];

    float*  wtab     = (float*)d_ws;
    float2* partials = (float2*)((char*)d_ws + WS_PARTIALS_OFF);

    build_w<<<1, C_COLS, 0, stream>>>(cidx_p, wtab);
    semi_loss_main<<<GRID, BLOCK, 0, stream>>>(out_p, outc_p, lab_p,
                                               mask_p, wtab, partials);
    semi_loss_reduce<<<1, BLOCK, 0, stream>>>(partials, (float*)d_out);
}